// Round 16
// baseline (214.200 us; speedup 1.0000x reference)
//
#include <hip/hip_runtime.h>
#include <stdint.h>

#define NTOT   12288
#define NW     192           // NTOT/64 bit-words
#define NCH    6
#define ECAP   1500000       // CSR entry capacity (24 MB)
#define CONF_THR 0.01f

typedef unsigned long long u64;
typedef uint32_t u32;

__device__ __forceinline__ float sigmf(float x){ return 1.0f/(1.0f+expf(-x)); }

// Exact equivalent of RN32(inter/d) >= 0.45f for d>0 (midpoint compare, exact in f64):
// m = (pred(0.45f)+0.45f)/2 = 30198987 * 2^-26 (25-bit); m*(double)d exact (<=49 bits).
__device__ __forceinline__ bool sup_exact(float4 a, float aar, float4 b, float bar){
  float tlx=fmaxf(a.x,b.x), tly=fmaxf(a.y,b.y);
  float brx=fminf(a.z,b.z), bry=fminf(a.w,b.w);
  float inter = __fmul_rn(__fsub_rn(brx,tlx), __fsub_rn(bry,tly));
  float d     = __fsub_rn(__fadd_rn(aar,bar), inter);
  bool ov = (tlx<brx) && (tly<bry);
  const double M = 30198987.0/67108864.0;
  return ov && ((double)inter >= M*(double)d);
}

// ---------------- decode (+ zero validw/ecnt for this call) ----------------
__global__ void k_decode(const float* __restrict__ feat, const float* __restrict__ anchors,
                         float4* __restrict__ obox, float* __restrict__ oobj,
                         float* __restrict__ ocls, float* __restrict__ oscore,
                         u32* __restrict__ okey, int* __restrict__ rank,
                         u64* __restrict__ validw, u32* __restrict__ ecnt){
  int n = blockIdx.x*256 + threadIdx.x;
  if(blockIdx.x==0){
    if(threadIdx.x<NW) validw[threadIdx.x]=0ull;
    if(threadIdx.x==NW) *ecnt=0u;
  }
  int a = n >> 12;
  int cell = n & 4095;
  int gy = cell >> 6, gx = cell & 63;
  const float* f = feat + a*NCH*4096 + cell;
  float v0=f[0], v1=f[4096], v2=f[8192], v3=f[12288], v4=f[16384], v5=f[20480];
  float aw = anchors[2*a]   * 0.125f;
  float ah = anchors[2*a+1] * 0.125f;
  float px = (sigmf(v0) + (float)gx) * 8.0f;
  float py = (sigmf(v1) + (float)gy) * 8.0f;
  float pw = (expf(v2)*aw) * 8.0f;
  float ph = (expf(v3)*ah) * 8.0f;
  float obj = sigmf(v4), cls = sigmf(v5);
  float4 b;
  b.x = px - pw*0.5f; b.y = py - ph*0.5f;
  b.z = px + pw*0.5f; b.w = py + ph*0.5f;
  float sc = obj*cls;
  obox[n]=b; oobj[n]=obj; ocls[n]=cls; oscore[n]=sc;
  u32 u = __float_as_uint(sc);
  u32 asc = (u & 0x80000000u) ? ~u : (u | 0x80000000u);
  okey[n] = ~asc;            // descending: higher score -> smaller key
  rank[n] = 0;
}

// ---------------- partial rank over a 1024-key slice ----------------
__global__ __launch_bounds__(256) void k_rank_part(const u32* __restrict__ okey,
                                                   int* __restrict__ rank){
  __shared__ u32 tile[1024];
  int n = blockIdx.x*256 + threadIdx.x;
  int t0 = blockIdx.y * 1024;
  u32 my = okey[n];
  for(int k=threadIdx.x;k<1024;k+=256) tile[k]=okey[t0+k];
  __syncthreads();
  int r0=0,r1=0,r2=0,r3=0;
  #pragma unroll 4
  for(int k=0;k<1024;k+=4){
    uint4 kj = *reinterpret_cast<const uint4*>(&tile[k]);
    int j = t0+k;
    r0 += (int)((kj.x<my)||(kj.x==my && (j  )<n));
    r1 += (int)((kj.y<my)||(kj.y==my && (j+1)<n));
    r2 += (int)((kj.z<my)||(kj.z==my && (j+2)<n));
    r3 += (int)((kj.w<my)||(kj.w==my && (j+3)<n));
  }
  atomicAdd(&rank[n], r0+r1+r2+r3);
}

// ---------------- scatter into sorted arrays + validw bits ----------------
__global__ void k_scatter(const int* __restrict__ rank,
                          const float4* __restrict__ obox,const float* __restrict__ oobj,
                          const float* __restrict__ ocls,const float* __restrict__ oscore,
                          float4* __restrict__ sbox,float* __restrict__ sarea,
                          float* __restrict__ sobj,float* __restrict__ scls,
                          int* __restrict__ order,u64* __restrict__ validw){
  int n = blockIdx.x*256 + threadIdx.x;
  int r = rank[n];
  float4 b = obox[n];
  sbox[r]=b;
  sarea[r]=(b.z-b.x)*(b.w-b.y);
  sobj[r]=oobj[n]; scls[r]=ocls[n];
  order[r]=n;
  if(oscore[n] >= CONF_THR)
    atomicOr(&validw[r>>6], 1ull<<(unsigned)(r&63));
}

// ---------------- CSR build: mirror-pair fused + manual unroll-2 (R14 verbatim) ----------------
__global__ __launch_bounds__(256) void k_cols(
    const float4* __restrict__ sbox, const float* __restrict__ sarea,
    const u64* __restrict__ validw_g,
    uint4* __restrict__ entries, uint2* __restrict__ boxOff, u32* __restrict__ ecnt)
{
  __shared__ uint4 stg[4][2][NW];       // per-wave, per-half staging (24.5 KB)
  __shared__ u64 vwL[NW];
  int tid=threadIdx.x, lane=tid&63, wvl=tid>>6;
  for(int t=tid;t<NW;t+=256) vwL[t]=validw_g[t];
  __syncthreads();
  int g  = blockIdx.x*4 + wvl;          // 0..6143
  int j1 = g, j2 = NTOT-1-g;
  bool val1 = (vwL[j1>>6]>>(unsigned)(j1&63))&1ull;
  bool val2 = (vwL[j2>>6]>>(unsigned)(j2&63))&1ull;
  float4 b1=sbox[j1], b2=sbox[j2];
  float ar1=sarea[j1], ar2=sarea[j2];
  int B1=j1>>6, B2=j2>>6;               // B1 < B2 always
  u32 cnt1=0, cnt2=0;
  int vend = val2 ? B2 : (val1 ? B1 : -1);
  int v = 0;
  for(; v+1<=vend; v+=2){
    int i0 = (v<<6)|lane, i1 = ((v+1)<<6)|lane;
    float4 a0 = sbox[i0];
    float4 a1 = sbox[i1];
    float ai0 = sarea[i0];
    float ai1 = sarea[i1];
    if(val2){
      bool s20 = (i0<j2) && sup_exact(a0,ai0,b2,ar2);
      bool s21 = (i1<j2) && sup_exact(a1,ai1,b2,ar2);
      u64 w20 = __ballot(s20) & vwL[v];
      u64 w21 = __ballot(s21) & vwL[v+1];
      if(w20){ if(lane==0) stg[wvl][1][cnt2]=make_uint4((u32)v,  (u32)w20,(u32)(w20>>32),0u); cnt2++; }
      if(w21){ if(lane==0) stg[wvl][1][cnt2]=make_uint4((u32)v+1,(u32)w21,(u32)(w21>>32),0u); cnt2++; }
    }
    if(val1 && v<=B1){
      bool s10 = (i0<j1) && sup_exact(a0,ai0,b1,ar1);
      bool s11 = (v+1<=B1) && (i1<j1) && sup_exact(a1,ai1,b1,ar1);
      u64 w10 = __ballot(s10) & vwL[v];
      u64 w11 = __ballot(s11) & vwL[v+1];
      if(w10){ if(lane==0) stg[wvl][0][cnt1]=make_uint4((u32)v,  (u32)w10,(u32)(w10>>32),0u); cnt1++; }
      if(w11){ if(lane==0) stg[wvl][0][cnt1]=make_uint4((u32)v+1,(u32)w11,(u32)(w11>>32),0u); cnt1++; }
    }
  }
  if(v<=vend){                          // odd tail word
    int i0 = (v<<6)|lane;
    float4 a0 = sbox[i0];
    float ai0 = sarea[i0];
    if(val2){
      bool s20 = (i0<j2) && sup_exact(a0,ai0,b2,ar2);
      u64 w20 = __ballot(s20) & vwL[v];
      if(w20){ if(lane==0) stg[wvl][1][cnt2]=make_uint4((u32)v,(u32)w20,(u32)(w20>>32),0u); cnt2++; }
    }
    if(val1 && v<=B1){
      bool s10 = (i0<j1) && sup_exact(a0,ai0,b1,ar1);
      u64 w10 = __ballot(s10) & vwL[v];
      if(w10){ if(lane==0) stg[wvl][0][cnt1]=make_uint4((u32)v,(u32)w10,(u32)(w10>>32),0u); cnt1++; }
    }
  }
  u32 tot = cnt1+cnt2, base=0;
  if(lane==0 && tot) base = atomicAdd(ecnt, tot);   // entry order irrelevant under OR
  base = (u32)__builtin_amdgcn_readfirstlane((int)base);
  if(lane==0){
    boxOff[j1]=make_uint2(base,      cnt1);
    boxOff[j2]=make_uint2(base+cnt1, cnt2);
  }
  asm volatile("s_waitcnt lgkmcnt(0)" ::: "memory");
  for(u32 e=lane;e<cnt1;e+=64) if(base+e<ECAP)      entries[base+e]     =stg[wvl][0][e];
  for(u32 e=lane;e<cnt2;e+=64) if(base+cnt1+e<ECAP) entries[base+cnt1+e]=stg[wvl][1][e];
}

// ---------------- Gauss-Seidel fixpoint + fused final output ----------------
__global__ __launch_bounds__(1024) void k_gsf(
    const u64* __restrict__ validw_g, const uint2* __restrict__ boxOff,
    const uint4* __restrict__ entries,
    const int* __restrict__ order, const float4* __restrict__ sbox,
    const float* __restrict__ sobj, const float* __restrict__ scls,
    float* __restrict__ out)
{
  __shared__ u64 kcur[NW], validL[NW];
  __shared__ u32 chg[2];
  int tid=threadIdx.x, lane=tid&63, wv=tid>>6;      // 16 waves x 12 words
  for(int t=tid;t<NW;t+=1024){ u64 v=validw_g[t]; validL[t]=v; kcur[t]=v; }
  if(tid<2) chg[tid]=0u;
  uint2 off[12];
  #pragma unroll
  for(int k=0;k<12;k++) off[k]=boxOff[((wv*12+k)<<6)|lane];
  __syncthreads();
  for(int r=0;;++r){
    int f=r&1;
    if(tid==0) chg[f^1]=0u;             // reset NEXT round's flag
    bool any=false;
    #pragma unroll 1
    for(int k=0;k<12;k++){
      int w = wv*12+k;
      u64 valw = validL[w];
      u64 old  = kcur[w];
      bool bv = (valw>>(unsigned)lane)&1ull;
      u32 base=off[k].x, cnt = bv ? off[k].y : 0u;
      bool killed=false;
      for(u32 e=0;e<cnt;e++){           // no break: loads issue as independent batch
        uint4 en = entries[base+e];
        killed |= (kcur[en.x] & ((((u64)en.z)<<32)|(u64)en.y)) != 0ull;
      }
      u64 nk = valw & ~__ballot(killed);
      if(nk != old){ any=true; if(lane==0) kcur[w]=nk; }
      asm volatile("s_waitcnt lgkmcnt(0)" ::: "memory");   // wave sees own write
    }
    if(any && lane==0) chg[f]=1u;       // benign same-value race
    __syncthreads();
    u32 c = chg[f];
    __syncthreads();                    // all read before anyone resets chg[f]
    if(!c) break;
  }
  __syncthreads();
  // fused final output: det (original order) + keep flags, straight from LDS kcur
  #pragma unroll 1
  for(int t=0;t<12;t++){
    int i = tid + t*1024;
    int n = order[i];
    u64 kw = kcur[i>>6];
    float kf = ((kw>>(unsigned)(i&63))&1ull) ? 1.0f : 0.0f;
    float4 b = sbox[i];
    float* det = out + (size_t)n*6;
    det[0]=b.x*kf; det[1]=b.y*kf; det[2]=b.z*kf; det[3]=b.w*kf;
    det[4]=sobj[i]*kf; det[5]=scls[i]*kf;
    out[NTOT*6 + n] = kf;
  }
}

extern "C" void kernel_launch(void* const* d_in,const int* in_sizes,int n_in,
                              void* d_out,int out_size,void* d_ws,size_t ws_size,
                              hipStream_t stream){
  const float* feat=(const float*)d_in[0];
  const float* anchors=(const float*)d_in[1];
  float* out=(float*)d_out;

  char* w=(char*)d_ws;
  auto alloc=[&](size_t bytes)->char*{ char* p=w; w += (bytes+255)&~255ull; return p; };
  float4 *obox =(float4*)alloc(NTOT*16);
  float  *oobj =(float*) alloc(NTOT*4);
  float  *ocls =(float*) alloc(NTOT*4);
  float  *oscore=(float*)alloc(NTOT*4);
  u32    *okey =(u32*)   alloc(NTOT*4);
  int    *rank =(int*)   alloc(NTOT*4);
  float4 *sbox =(float4*)alloc(NTOT*16);
  float  *sarea=(float*) alloc(NTOT*4);
  float  *sobj =(float*) alloc(NTOT*4);
  float  *scls =(float*) alloc(NTOT*4);
  int    *order=(int*)   alloc(NTOT*4);
  u64    *validw =(u64*) alloc(NW*8);
  u32    *ecnt   =(u32*) alloc(256);
  uint2  *boxOff =(uint2*)alloc((size_t)NTOT*8);
  uint4  *entries=(uint4*)alloc((size_t)ECAP*16);   // 24 MB CSR entries

  hipLaunchKernelGGL(k_decode, dim3(NTOT/256),dim3(256),0,stream,
                     feat,anchors,obox,oobj,ocls,oscore,okey,rank,validw,ecnt);
  hipLaunchKernelGGL(k_rank_part, dim3(NTOT/256,12),dim3(256),0,stream, okey,rank);
  hipLaunchKernelGGL(k_scatter, dim3(NTOT/256),dim3(256),0,stream,
                     rank,obox,oobj,ocls,oscore,sbox,sarea,sobj,scls,order,validw);
  hipLaunchKernelGGL(k_cols, dim3(NTOT/8),dim3(256),0,stream,
                     sbox,sarea,validw,entries,boxOff,ecnt);
  hipLaunchKernelGGL(k_gsf, dim3(1),dim3(1024),0,stream,
                     validw,boxOff,entries,order,sbox,sobj,scls,out);
}

// Round 17
// 167.806 us; speedup vs baseline: 1.2765x; 1.2765x over previous
//
#include <hip/hip_runtime.h>
#include <stdint.h>

#define NTOT   12288
#define NW     192           // NTOT/64 bit-words
#define NCH    6
#define ECAP   1500000       // CSR entry capacity (24 MB)
#define CAP    64            // staged entries per (wave, half); overflow -> exact re-walk
#define CONF_THR 0.01f

typedef unsigned long long u64;
typedef uint32_t u32;

__device__ __forceinline__ float sigmf(float x){ return 1.0f/(1.0f+expf(-x)); }

// Exact equivalent of RN32(inter/d) >= 0.45f for d>0 (midpoint compare, exact in f64):
// m = (pred(0.45f)+0.45f)/2 = 30198987 * 2^-26 (25-bit); m*(double)d exact (<=49 bits).
__device__ __forceinline__ bool sup_exact(float4 a, float aar, float4 b, float bar){
  float tlx=fmaxf(a.x,b.x), tly=fmaxf(a.y,b.y);
  float brx=fminf(a.z,b.z), bry=fminf(a.w,b.w);
  float inter = __fmul_rn(__fsub_rn(brx,tlx), __fsub_rn(bry,tly));
  float d     = __fsub_rn(__fadd_rn(aar,bar), inter);
  bool ov = (tlx<brx) && (tly<bry);
  const double M = 30198987.0/67108864.0;
  return ov && ((double)inter >= M*(double)d);
}

// ---------------- decode (+ zero validw/ecnt for this call) ----------------
__global__ void k_decode(const float* __restrict__ feat, const float* __restrict__ anchors,
                         float4* __restrict__ obox, float* __restrict__ oobj,
                         float* __restrict__ ocls, float* __restrict__ oscore,
                         u32* __restrict__ okey, int* __restrict__ rank,
                         u64* __restrict__ validw, u32* __restrict__ ecnt){
  int n = blockIdx.x*256 + threadIdx.x;
  if(blockIdx.x==0){
    if(threadIdx.x<NW) validw[threadIdx.x]=0ull;
    if(threadIdx.x==NW) *ecnt=0u;
  }
  int a = n >> 12;
  int cell = n & 4095;
  int gy = cell >> 6, gx = cell & 63;
  const float* f = feat + a*NCH*4096 + cell;
  float v0=f[0], v1=f[4096], v2=f[8192], v3=f[12288], v4=f[16384], v5=f[20480];
  float aw = anchors[2*a]   * 0.125f;
  float ah = anchors[2*a+1] * 0.125f;
  float px = (sigmf(v0) + (float)gx) * 8.0f;
  float py = (sigmf(v1) + (float)gy) * 8.0f;
  float pw = (expf(v2)*aw) * 8.0f;
  float ph = (expf(v3)*ah) * 8.0f;
  float obj = sigmf(v4), cls = sigmf(v5);
  float4 b;
  b.x = px - pw*0.5f; b.y = py - ph*0.5f;
  b.z = px + pw*0.5f; b.w = py + ph*0.5f;
  float sc = obj*cls;
  obox[n]=b; oobj[n]=obj; ocls[n]=cls; oscore[n]=sc;
  u32 u = __float_as_uint(sc);
  u32 asc = (u & 0x80000000u) ? ~u : (u | 0x80000000u);
  okey[n] = ~asc;            // descending: higher score -> smaller key
  rank[n] = 0;
}

// ---------------- partial rank over a 1024-key slice ----------------
__global__ __launch_bounds__(256) void k_rank_part(const u32* __restrict__ okey,
                                                   int* __restrict__ rank){
  __shared__ u32 tile[1024];
  int n = blockIdx.x*256 + threadIdx.x;
  int t0 = blockIdx.y * 1024;
  u32 my = okey[n];
  for(int k=threadIdx.x;k<1024;k+=256) tile[k]=okey[t0+k];
  __syncthreads();
  int r0=0,r1=0,r2=0,r3=0;
  #pragma unroll 4
  for(int k=0;k<1024;k+=4){
    uint4 kj = *reinterpret_cast<const uint4*>(&tile[k]);
    int j = t0+k;
    r0 += (int)((kj.x<my)||(kj.x==my && (j  )<n));
    r1 += (int)((kj.y<my)||(kj.y==my && (j+1)<n));
    r2 += (int)((kj.z<my)||(kj.z==my && (j+2)<n));
    r3 += (int)((kj.w<my)||(kj.w==my && (j+3)<n));
  }
  atomicAdd(&rank[n], r0+r1+r2+r3);
}

// ---------------- scatter into sorted arrays + validw bits ----------------
__global__ void k_scatter(const int* __restrict__ rank,
                          const float4* __restrict__ obox,const float* __restrict__ oobj,
                          const float* __restrict__ ocls,const float* __restrict__ oscore,
                          float4* __restrict__ sbox,float* __restrict__ sarea,
                          float* __restrict__ sobj,float* __restrict__ scls,
                          int* __restrict__ order,u64* __restrict__ validw){
  int n = blockIdx.x*256 + threadIdx.x;
  int r = rank[n];
  float4 b = obox[n];
  sbox[r]=b;
  sarea[r]=(b.z-b.x)*(b.w-b.y);
  sobj[r]=oobj[n]; scls[r]=ocls[n];
  order[r]=n;
  if(oscore[n] >= CONF_THR)
    atomicOr(&validw[r>>6], 1ull<<(unsigned)(r&63));
}

// ---------------- CSR build: mirror-pair + unroll-2, small LDS staging ----------------
__global__ __launch_bounds__(256) void k_cols(
    const float4* __restrict__ sbox, const float* __restrict__ sarea,
    const u64* __restrict__ validw_g,
    uint4* __restrict__ entries, uint2* __restrict__ boxOff, u32* __restrict__ ecnt)
{
  __shared__ uint4 stg[4][2][CAP];      // 8 KB
  __shared__ u64 vwL[NW];               // 1.5 KB
  int tid=threadIdx.x, lane=tid&63, wvl=tid>>6;
  for(int t=tid;t<NW;t+=256) vwL[t]=validw_g[t];
  __syncthreads();
  int g  = blockIdx.x*4 + wvl;          // 0..6143
  int j1 = g, j2 = NTOT-1-g;
  bool val1 = (vwL[j1>>6]>>(unsigned)(j1&63))&1ull;
  bool val2 = (vwL[j2>>6]>>(unsigned)(j2&63))&1ull;
  float4 b1=sbox[j1], b2=sbox[j2];
  float ar1=sarea[j1], ar2=sarea[j2];
  int B1=j1>>6, B2=j2>>6;               // B1 < B2 always
  u32 cnt1=0, cnt2=0;
  int vend = val2 ? B2 : (val1 ? B1 : -1);
  int v = 0;
  for(; v+1<=vend; v+=2){
    int i0 = (v<<6)|lane, i1 = ((v+1)<<6)|lane;
    float4 a0 = sbox[i0];
    float4 a1 = sbox[i1];
    float ai0 = sarea[i0];
    float ai1 = sarea[i1];
    if(val2){
      bool s20 = (i0<j2) && sup_exact(a0,ai0,b2,ar2);
      bool s21 = (i1<j2) && sup_exact(a1,ai1,b2,ar2);
      u64 w20 = __ballot(s20) & vwL[v];
      u64 w21 = __ballot(s21) & vwL[v+1];
      if(w20){ if(lane==0 && cnt2<CAP) stg[wvl][1][cnt2]=make_uint4((u32)v,  (u32)w20,(u32)(w20>>32),0u); cnt2++; }
      if(w21){ if(lane==0 && cnt2<CAP) stg[wvl][1][cnt2]=make_uint4((u32)(v+1),(u32)w21,(u32)(w21>>32),0u); cnt2++; }
    }
    if(val1 && v<=B1){
      bool s10 = (i0<j1) && sup_exact(a0,ai0,b1,ar1);
      bool s11 = (v+1<=B1) && (i1<j1) && sup_exact(a1,ai1,b1,ar1);
      u64 w10 = __ballot(s10) & vwL[v];
      u64 w11 = __ballot(s11) & vwL[v+1];
      if(w10){ if(lane==0 && cnt1<CAP) stg[wvl][0][cnt1]=make_uint4((u32)v,  (u32)w10,(u32)(w10>>32),0u); cnt1++; }
      if(w11){ if(lane==0 && cnt1<CAP) stg[wvl][0][cnt1]=make_uint4((u32)(v+1),(u32)w11,(u32)(w11>>32),0u); cnt1++; }
    }
  }
  if(v<=vend){                          // odd tail word
    int i0 = (v<<6)|lane;
    float4 a0 = sbox[i0];
    float ai0 = sarea[i0];
    if(val2){
      bool s20 = (i0<j2) && sup_exact(a0,ai0,b2,ar2);
      u64 w20 = __ballot(s20) & vwL[v];
      if(w20){ if(lane==0 && cnt2<CAP) stg[wvl][1][cnt2]=make_uint4((u32)v,(u32)w20,(u32)(w20>>32),0u); cnt2++; }
    }
    if(val1 && v<=B1){
      bool s10 = (i0<j1) && sup_exact(a0,ai0,b1,ar1);
      u64 w10 = __ballot(s10) & vwL[v];
      if(w10){ if(lane==0 && cnt1<CAP) stg[wvl][0][cnt1]=make_uint4((u32)v,(u32)w10,(u32)(w10>>32),0u); cnt1++; }
    }
  }
  u32 tot = cnt1+cnt2, base=0;
  if(lane==0 && tot) base = atomicAdd(ecnt, tot);   // entry order irrelevant under OR
  base = (u32)__builtin_amdgcn_readfirstlane((int)base);
  if(lane==0){
    boxOff[j1]=make_uint2(base,      cnt1);
    boxOff[j2]=make_uint2(base+cnt1, cnt2);
  }
  asm volatile("s_waitcnt lgkmcnt(0)" ::: "memory");
  if(cnt1<=CAP){
    for(u32 e=lane;e<cnt1;e+=64) if(base+e<ECAP) entries[base+e]=stg[wvl][0][e];
  } else {
    u32 pos=0;                          // rare exact re-walk (same order -> same count)
    for(int vv=0; vv<=B1; ++vv){
      int i=(vv<<6)|lane;
      float4 a=sbox[i]; float ai=sarea[i];
      bool s=(i<j1)&&sup_exact(a,ai,b1,ar1);
      u64 wb=__ballot(s)&vwL[vv];
      if(wb){ if(lane==0 && base+pos<ECAP) entries[base+pos]=make_uint4((u32)vv,(u32)wb,(u32)(wb>>32),0u); pos++; }
    }
  }
  if(cnt2<=CAP){
    for(u32 e=lane;e<cnt2;e+=64) if(base+cnt1+e<ECAP) entries[base+cnt1+e]=stg[wvl][1][e];
  } else {
    u32 pos=0;
    for(int vv=0; vv<=B2; ++vv){
      int i=(vv<<6)|lane;
      float4 a=sbox[i]; float ai=sarea[i];
      bool s=(i<j2)&&sup_exact(a,ai,b2,ar2);
      u64 wb=__ballot(s)&vwL[vv];
      if(wb){ if(lane==0 && base+cnt1+pos<ECAP) entries[base+cnt1+pos]=make_uint4((u32)vv,(u32)wb,(u32)(wb>>32),0u); pos++; }
    }
  }
}

// ---------------- in-place Gauss-Seidel fixpoint = exact greedy NMS ----------------
__global__ __launch_bounds__(1024) void k_gs(
    const u64* __restrict__ validw_g, const uint2* __restrict__ boxOff,
    const uint4* __restrict__ entries, u64* __restrict__ keepw_g)
{
  __shared__ u64 kcur[NW], validL[NW];
  __shared__ u32 chg[2];
  int tid=threadIdx.x, lane=tid&63, wv=tid>>6;      // 16 waves x 12 words
  for(int t=tid;t<NW;t+=1024){ u64 v=validw_g[t]; validL[t]=v; kcur[t]=v; }
  if(tid<2) chg[tid]=0u;
  uint2 off[12];
  #pragma unroll
  for(int k=0;k<12;k++) off[k]=boxOff[((wv*12+k)<<6)|lane];
  __syncthreads();
  for(int r=0;;++r){
    int f=r&1;
    if(tid==0) chg[f^1]=0u;             // reset NEXT round's flag
    bool any=false;
    #pragma unroll 1
    for(int k=0;k<12;k++){
      int w = wv*12+k;
      u64 valw = validL[w];
      u64 old  = kcur[w];
      bool bv = (valw>>(unsigned)lane)&1ull;
      u32 base=off[k].x, cnt = bv ? off[k].y : 0u;
      bool killed=false;
      for(u32 e=0;e<cnt;e++){
        uint4 en = entries[base+e];
        if(kcur[en.x] & ((((u64)en.z)<<32)|(u64)en.y)){ killed=true; break; }
      }
      u64 nk = valw & ~__ballot(killed);
      if(nk != old){ any=true; if(lane==0) kcur[w]=nk; }
      asm volatile("s_waitcnt lgkmcnt(0)" ::: "memory");   // wave sees own write
    }
    if(any && lane==0) chg[f]=1u;       // benign same-value race
    __syncthreads();
    u32 c = chg[f];
    __syncthreads();                    // all read before anyone resets chg[f]
    if(!c) break;
  }
  for(int t=tid;t<NW;t+=1024) keepw_g[t]=kcur[t];
}

// ---------------- final output ----------------
__global__ void k_final(const int* __restrict__ order,const u64* __restrict__ keepw,
                        const float4* __restrict__ sbox,const float* __restrict__ sobj,
                        const float* __restrict__ scls,float* __restrict__ out){
  int i = blockIdx.x*256 + threadIdx.x;
  int n = order[i];
  u64 kw = keepw[i>>6];
  float kf = ((kw>>(unsigned)(i&63))&1ull) ? 1.0f : 0.0f;
  float4 b = sbox[i];
  float* det = out + (size_t)n*6;
  det[0]=b.x*kf; det[1]=b.y*kf; det[2]=b.z*kf; det[3]=b.w*kf;
  det[4]=sobj[i]*kf; det[5]=scls[i]*kf;
  out[NTOT*6 + n] = kf;
}

extern "C" void kernel_launch(void* const* d_in,const int* in_sizes,int n_in,
                              void* d_out,int out_size,void* d_ws,size_t ws_size,
                              hipStream_t stream){
  const float* feat=(const float*)d_in[0];
  const float* anchors=(const float*)d_in[1];
  float* out=(float*)d_out;

  char* w=(char*)d_ws;
  auto alloc=[&](size_t bytes)->char*{ char* p=w; w += (bytes+255)&~255ull; return p; };
  float4 *obox =(float4*)alloc(NTOT*16);
  float  *oobj =(float*) alloc(NTOT*4);
  float  *ocls =(float*) alloc(NTOT*4);
  float  *oscore=(float*)alloc(NTOT*4);
  u32    *okey =(u32*)   alloc(NTOT*4);
  int    *rank =(int*)   alloc(NTOT*4);
  float4 *sbox =(float4*)alloc(NTOT*16);
  float  *sarea=(float*) alloc(NTOT*4);
  float  *sobj =(float*) alloc(NTOT*4);
  float  *scls =(float*) alloc(NTOT*4);
  int    *order=(int*)   alloc(NTOT*4);
  u64    *validw =(u64*) alloc(NW*8);
  u64    *keepw  =(u64*) alloc(NW*8);
  u32    *ecnt   =(u32*) alloc(256);
  uint2  *boxOff =(uint2*)alloc((size_t)NTOT*8);
  uint4  *entries=(uint4*)alloc((size_t)ECAP*16);   // 24 MB CSR entries

  hipLaunchKernelGGL(k_decode, dim3(NTOT/256),dim3(256),0,stream,
                     feat,anchors,obox,oobj,ocls,oscore,okey,rank,validw,ecnt);
  hipLaunchKernelGGL(k_rank_part, dim3(NTOT/256,12),dim3(256),0,stream, okey,rank);
  hipLaunchKernelGGL(k_scatter, dim3(NTOT/256),dim3(256),0,stream,
                     rank,obox,oobj,ocls,oscore,sbox,sarea,sobj,scls,order,validw);
  hipLaunchKernelGGL(k_cols, dim3(NTOT/8),dim3(256),0,stream,
                     sbox,sarea,validw,entries,boxOff,ecnt);
  hipLaunchKernelGGL(k_gs, dim3(1),dim3(1024),0,stream,
                     validw,boxOff,entries,keepw);
  hipLaunchKernelGGL(k_final, dim3(NTOT/256),dim3(256),0,stream,
                     order,keepw,sbox,sobj,scls,out);
}